// Round 1
// baseline (9878.931 us; speedup 1.0000x reference)
//
#include <hip/hip_runtime.h>
#include <math.h>

#define NTOT 3840
#define KTOT 3968   // 3840 neurons + 128 inputs
#define BATCH 32
#define TSTEPS 100
#define NIN 128
#define NOUT 3
#define NCHUNK 16
#define CHUNK 248   // KTOT / NCHUNK
#define NCOLT 15    // column tiles of 256
#define COLS 256

__device__ __forceinline__ bool is_dend(int k){
  return (k>=512 && k<1536) || (k>=2432 && k<3456);
}
__device__ __forceinline__ bool is_inh(int k){
  return (k>=1536 && k<1920) || (k>=3456 && k<3840);
}

// ---------------- init: h=0, ime=0, r0 = f(h0) (signed), x_0 appended ----------------
__global__ void k_init(const float* __restrict__ x, float* __restrict__ r0,
                       float* __restrict__ h, float* __restrict__ ime){
  int i = blockIdx.x*blockDim.x + threadIdx.x;
  int nthr = gridDim.x*blockDim.x;
  for (int e=i; e<BATCH*NTOT; e+=nthr) h[e]=0.f;
  for (int e=i; e<BATCH*1024; e+=nthr) ime[e]=0.f;
  for (int e=i; e<KTOT*BATCH; e+=nthr){
    int k = e>>5, b = e&31;            // r layout [k][b]
    float v;
    if (k < NTOT) v = is_dend(k) ? 0.5f : 0.f;   // sigmoid(0)=0.5, relu(0)=0 (sign moot: 0)
    else          v = x[b*NIN + (k-NTOT)];
    r0[e] = v;
  }
}

// ---------------- matmul partials: partial[c][b][n] = sum_{k in chunk} r[k][b]*w_eff[k][n] ----
__global__ __launch_bounds__(256) void k_matmul(const float* __restrict__ w_rec,
    const float* __restrict__ w_in, const float* __restrict__ r,
    float* __restrict__ partial){
  __shared__ float rlds[CHUNK*BATCH];           // 31744 B
  const int wg  = blockIdx.x;
  const int c   = wg / NCOLT;                   // K-chunk
  const int ct  = wg % NCOLT;                   // column tile
  const int tid = threadIdx.x;
  const int kBase = c * CHUNK;

  // stage signed-rate chunk into LDS (contiguous, coalesced float4)
  {
    const float4* rs4 = (const float4*)(r + (size_t)kBase*BATCH);
    float4* rl4 = (float4*)rlds;
    for (int e = tid; e < CHUNK*BATCH/4; e += 256) rl4[e] = rs4[e];
  }
  __syncthreads();

  const int tb = tid >> 6;                      // batch group: 8 b each
  const int tn = tid & 63;
  const int n0 = ct*COLS + tn*4;                // this thread's 4 columns

  float acc[8][4];
  #pragma unroll
  for (int i=0;i<8;i++){
    #pragma unroll
    for (int j=0;j<4;j++) acc[i][j]=0.f;
  }

  bool colSr[4], colPfc[4];
  #pragma unroll
  for (int j=0;j<4;j++){
    int n = n0+j;
    colSr[j]  = (n < 512);                      // SR_ES cols
    colPfc[j] = (n >= 1920 && n < 2432);        // PFC_ES cols
  }

  #pragma unroll 2
  for (int k=0; k<CHUNK; k++){
    const int kk = kBase + k;
    float wv[4];
    if (kk < NTOT){
      float4 w4 = *(const float4*)(w_rec + (size_t)kk*NTOT + n0);
      wv[0]=fabsf(w4.x); wv[1]=fabsf(w4.y); wv[2]=fabsf(w4.z); wv[3]=fabsf(w4.w);
      const bool rowSr  = (kk>=512  && kk<1536);
      const bool rowPfc = (kk>=2432 && kk<3456);
      #pragma unroll
      for (int j=0;j<4;j++){
        if ((rowSr && colSr[j]) || (rowPfc && colPfc[j])) wv[j]=0.f;
      }
    } else {
      float4 w4 = *(const float4*)(w_in + (size_t)(kk-NTOT)*NTOT + n0);
      wv[0]=w4.x; wv[1]=w4.y; wv[2]=w4.z; wv[3]=w4.w;
    }
    float4 ra = *(const float4*)&rlds[k*BATCH + tb*8];
    float4 rb = *(const float4*)&rlds[k*BATCH + tb*8 + 4];
    const float rv[8] = {ra.x,ra.y,ra.z,ra.w, rb.x,rb.y,rb.z,rb.w};
    #pragma unroll
    for (int i=0;i<8;i++){
      #pragma unroll
      for (int j=0;j<4;j++) acc[i][j] += rv[i]*wv[j];
    }
  }

  // diagonal correction: mask has zero diagonal
  #pragma unroll
  for (int j=0;j<4;j++){
    const int n = n0+j;
    if (n >= kBase && n < kBase+CHUNK && n < NTOT){
      const float wd = fabsf(w_rec[(size_t)n*NTOT + n]);
      #pragma unroll
      for (int i=0;i<8;i++) acc[i][j] -= rlds[(n-kBase)*BATCH + tb*8 + i]*wd;
    }
  }

  // store partial[c][b][n]
  #pragma unroll
  for (int i=0;i<8;i++){
    const int b = tb*8+i;
    float4 st; st.x=acc[i][0]; st.y=acc[i][1]; st.z=acc[i][2]; st.w=acc[i][3];
    *(float4*)(partial + ((size_t)(c*BATCH+b))*NTOT + n0) = st;
  }
}

// ---------------- per-step update: reduce partials + couplings + mGluR + h + r_next + readout ----
__global__ __launch_bounds__(256) void k_update(
    const float* __restrict__ partial, const float* __restrict__ bvec,
    const float* __restrict__ d2s, const float* __restrict__ noise_t,
    const float* __restrict__ x_next, const float* __restrict__ rcur,
    float* __restrict__ rnext, float* __restrict__ h, float* __restrict__ ime,
    const float* __restrict__ w_out, const float* __restrict__ b_out,
    float* __restrict__ out_t, int hasNext)
{
  const int tid0 = blockIdx.x*256 + threadIdx.x;
  const int nthr = gridDim.x*256;
  const float NS = sqrtf(0.4f)*0.01f;              // sqrt(2*decay)*noise_std
  const float LN10 = 2.302585092994046f;
  const float CEXP = 1.6989700043360187f/511.0f;   // (log10(5000)-2)/511

  for (int e = tid0; e < BATCH*NTOT; e += nthr){
    const int b = e / NTOT, n = e % NTOT;
    float pre = bvec[n];
    #pragma unroll
    for (int c=0;c<NCHUNK;c++) pre += partial[(size_t)c*BATCH*NTOT + e];

    if (n < 512){                                   // SR dend -> SR E soma
      pre += rcur[(512 +n)*BATCH+b]*d2s[n]     + rcur[(1024+n)*BATCH+b]*d2s[512+n];
    } else if (n >= 1920 && n < 2432){              // PFC dend -> PFC E soma
      const int j = n-1920;
      pre += rcur[(2432+j)*BATCH+b]*d2s[1024+j] + rcur[(2944+j)*BATCH+b]*d2s[1536+j];
    }
    if (n >= 2432 && n < 3456){                     // mGluR on PFC E dend
      const int j = n-2432;
      const float alpha = expf(-LN10*(1.0f + CEXP*(float)(j & 511)));
      const float imn = (1.f-alpha)*ime[b*1024+j] + alpha*fmaxf(pre,0.f);
      ime[b*1024+j] = imn;
      pre += imn;
    }
    const float hn = 0.8f*h[e] + 0.2f*pre + NS*noise_t[e];
    h[e] = hn;
    float rv = is_dend(n) ? (1.f/(1.f+expf(-hn))) : fmaxf(hn,0.f);
    if (is_inh(n)) rv = -rv;                        // fold Dale sign into r
    rnext[n*BATCH + b] = rv;
  }

  if (hasNext){
    for (int q = tid0; q < BATCH*NIN; q += nthr){
      const int b = q/NIN, j = q%NIN;
      rnext[(NTOT+j)*BATCH + b] = x_next[q];
    }
  }

  // readout out_t = r_t[:,SR_ES] @ w_out + b_out : one wave per (b,o)
  const int wave = tid0 >> 6;
  if (wave < BATCH*NOUT){
    const int lane = threadIdx.x & 63;
    const int b = wave / NOUT, o = wave % NOUT;
    float s = 0.f;
    for (int k = lane; k < 512; k += 64) s += rcur[k*BATCH+b]*w_out[k*NOUT+o];
    #pragma unroll
    for (int off=32; off; off>>=1) s += __shfl_down(s, off);
    if (lane==0) out_t[b*NOUT+o] = s + b_out[o];
  }
}

extern "C" void kernel_launch(void* const* d_in, const int* in_sizes, int n_in,
                              void* d_out, int out_size, void* d_ws, size_t ws_size,
                              hipStream_t stream) {
  const float* x     = (const float*)d_in[0];   // [100,32,128]
  const float* noise = (const float*)d_in[1];   // [100,32,3840]
  const float* w_rec = (const float*)d_in[2];   // [3840,3840]
  const float* w_in  = (const float*)d_in[3];   // [128,3840]
  const float* bvec  = (const float*)d_in[4];   // [3840]
  const float* d2s   = (const float*)d_in[5];   // [2048]
  const float* w_out = (const float*)d_in[6];   // [512,3]
  const float* b_out = (const float*)d_in[7];   // [3]
  // d_in[8] = mask: derived analytically, never read
  float* out = (float*)d_out;                   // [100,32,3]

  float* ws      = (float*)d_ws;
  float* partial = ws;                                  // 16*32*3840 = 1,966,080 f
  float* r0      = partial + (size_t)NCHUNK*BATCH*NTOT; // 126,976 f
  float* r1      = r0 + (size_t)KTOT*BATCH;
  float* h       = r1 + (size_t)KTOT*BATCH;             // 122,880 f
  float* ime     = h  + (size_t)BATCH*NTOT;             // 32,768 f

  k_init<<<256,256,0,stream>>>(x, r0, h, ime);
  for (int t=0; t<TSTEPS; t++){
    float* rc = (t&1) ? r1 : r0;
    float* rn = (t&1) ? r0 : r1;
    k_matmul<<<NCHUNK*NCOLT,256,0,stream>>>(w_rec, w_in, rc, partial);
    k_update<<<240,256,0,stream>>>(partial, bvec, d2s,
        noise + (size_t)t*BATCH*NTOT,
        x + (size_t)(t+1)*BATCH*NIN,
        rc, rn, h, ime, w_out, b_out,
        out + (size_t)t*BATCH*NOUT,
        (t+1<TSTEPS) ? 1 : 0);
  }
}

// Round 2
// 2460.975 us; speedup vs baseline: 4.0142x; 4.0142x over previous
//
#include <hip/hip_runtime.h>
#include <math.h>

typedef _Float16 f16;
typedef f16 f16x8 __attribute__((ext_vector_type(8)));
typedef float f32x4 __attribute__((ext_vector_type(4)));

#define NTOT 3840
#define KP   3968          // 3840 neurons + 128 inputs
#define BATCH 32
#define TSTEPS 100
#define NIN 128
#define NCHUNK 31          // K chunks of 128
#define CHUNK_F 122880     // 32*3840 floats per partial chunk

__device__ __forceinline__ bool is_dend(int k){
  return (k>=512 && k<1536) || (k>=2432 && k<3456);
}
__device__ __forceinline__ ushort f2h(float v){ f16 h=(f16)v; return *(ushort*)&h; }
__device__ __forceinline__ float h2f(ushort u){ f16 h=*(f16*)&u; return (float)h; }

// ---------- one-time: W_T[n][k] = fp16( |w_rec[k][n]| * mask[k][n] ), w_in rows appended ----------
__global__ __launch_bounds__(256) void k_prep_w(const float* __restrict__ w_rec,
    const float* __restrict__ w_in, const float* __restrict__ mask,
    ushort* __restrict__ WT){
  __shared__ ushort tile[64][72];
  const int bid = blockIdx.x;
  const int kt = bid / 60, nt = bid % 60;
  const int k0 = kt*64, n0 = nt*64;
  const int t = threadIdx.x;
  const int tr = t>>2, tq = t&3;
  const int k = k0 + tr;
  const int cbase = n0 + tq*16;
  if (k < NTOT){
    #pragma unroll
    for (int q=0;q<4;q++){
      float4 w = *(const float4*)(w_rec + (size_t)k*NTOT + cbase + q*4);
      float4 m = *(const float4*)(mask  + (size_t)k*NTOT + cbase + q*4);
      tile[tr][tq*16+q*4+0] = f2h(fabsf(w.x)*m.x);
      tile[tr][tq*16+q*4+1] = f2h(fabsf(w.y)*m.y);
      tile[tr][tq*16+q*4+2] = f2h(fabsf(w.z)*m.z);
      tile[tr][tq*16+q*4+3] = f2h(fabsf(w.w)*m.w);
    }
  } else {
    const float* src = w_in + (size_t)(k-NTOT)*NTOT + cbase;
    #pragma unroll
    for (int q=0;q<4;q++){
      float4 w = *(const float4*)(src + q*4);
      tile[tr][tq*16+q*4+0] = f2h(w.x);
      tile[tr][tq*16+q*4+1] = f2h(w.y);
      tile[tr][tq*16+q*4+2] = f2h(w.z);
      tile[tr][tq*16+q*4+3] = f2h(w.w);
    }
  }
  __syncthreads();
  const int n  = n0 + tr;
  const int kq = tq*16;
  uint u[8];
  #pragma unroll
  for (int q=0;q<8;q++)
    u[q] = (uint)tile[kq+2*q][tr] | ((uint)tile[kq+2*q+1][tr] << 16);
  uint4* dst = (uint4*)(WT + (size_t)n*KP + k0 + kq);
  dst[0] = make_uint4(u[0],u[1],u[2],u[3]);
  dst[1] = make_uint4(u[4],u[5],u[6],u[7]);
}

// ---------- init: h=0, ime=0, r0[b][k] = rate(h0) for k<3840, x_0 for k>=3840 ----------
__global__ void k_init(const float* __restrict__ x, ushort* __restrict__ r0,
                       float* __restrict__ h, float* __restrict__ ime){
  int i = blockIdx.x*blockDim.x + threadIdx.x;
  int nthr = gridDim.x*blockDim.x;
  for (int e=i; e<BATCH*NTOT; e+=nthr) h[e]=0.f;
  for (int e=i; e<BATCH*1024; e+=nthr) ime[e]=0.f;
  for (int e=i; e<BATCH*KP; e+=nthr){
    int b = e / KP, k = e % KP;
    float v = (k<NTOT) ? (is_dend(k)?0.5f:0.f) : x[b*NIN + (k-NTOT)];
    r0[e] = f2h(v);
  }
}

// ---------- matmul: partial[c] += R[32 x 128-chunk] @ W[chunk x 3840] via MFMA ----------
// grid: 31 chunks x 32 slots (30 N-tiles of 128 + 2 idle). WG = 4 waves:
//   kw = K-subwave (2 x 64K), nw = N-subtile (2 x 64 cols). Wave tile: 32b x 64n.
__global__ __launch_bounds__(256) void k_matmul(const ushort* __restrict__ WTu,
    const ushort* __restrict__ Ru, float* __restrict__ partial){
  __shared__ f32x4 red[2][8][64];              // 16 KB
  const int bid = blockIdx.x;
  const int c = bid >> 5;
  const int s = bid & 31;
  const int vnt = (s&7)*4 + (s>>3);            // XCD (bid%8) owns 4 fixed N-stripes
  if (vnt >= 30) return;
  const int tid = threadIdx.x;
  const int wv = tid >> 6, lane = tid & 63;
  const int kw = wv & 1, nw = wv >> 1;
  const int n0 = vnt*128 + nw*64;
  const int kbase = c*128 + kw*64;
  const int l15 = lane & 15, lh = lane >> 4;
  const f16* WT = (const f16*)WTu;
  const f16* R  = (const f16*)Ru;

  f32x4 acc[8];
  #pragma unroll
  for (int f=0; f<8; f++){ acc[f].x=0.f; acc[f].y=0.f; acc[f].z=0.f; acc[f].w=0.f; }

  #pragma unroll
  for (int st=0; st<2; st++){
    const int k = kbase + st*32 + lh*8;
    f16x8 a0 = *(const f16x8*)(R + (size_t)(l15     )*KP + k);
    f16x8 a1 = *(const f16x8*)(R + (size_t)(16 + l15)*KP + k);
    #pragma unroll
    for (int nf=0; nf<4; nf++){
      f16x8 bf = *(const f16x8*)(WT + (size_t)(n0 + nf*16 + l15)*KP + k);
      acc[nf]   = __builtin_amdgcn_mfma_f32_16x16x32_f16(a0, bf, acc[nf],   0,0,0);
      acc[4+nf] = __builtin_amdgcn_mfma_f32_16x16x32_f16(a1, bf, acc[4+nf], 0,0,0);
    }
  }
  if (kw == 1){
    #pragma unroll
    for (int f=0; f<8; f++) red[nw][f][lane] = acc[f];
  }
  __syncthreads();
  if (kw == 0){
    float* out = partial + (size_t)c*CHUNK_F + (size_t)(vnt*2+nw)*2048;
    #pragma unroll
    for (int f=0; f<8; f++){
      f32x4 v = acc[f] + red[nw][f][lane];
      *(f32x4*)(out + (f*64 + lane)*4) = v;
    }
  }
}

// ---------- per-step update: reduce partials + couplings + mGluR + leak + rates + readout ----------
__global__ __launch_bounds__(256) void k_update(
    const float* __restrict__ partial, const float* __restrict__ bvec,
    const float* __restrict__ d2s, const float* __restrict__ noise_t,
    const float* __restrict__ x_next, const ushort* __restrict__ rcur,
    ushort* __restrict__ rnext, float* __restrict__ h, float* __restrict__ ime,
    const float* __restrict__ w_out, const float* __restrict__ b_out,
    float* __restrict__ out_t, int hasNext)
{
  const int tid0 = blockIdx.x*256 + threadIdx.x;
  const int nthr = gridDim.x*256;
  const float NS = 0.0063245553203367585f;           // sqrt(2*0.2)*0.01
  const float LN10 = 2.302585092994046f;
  const float CEXP = 1.6989700043360187f/511.0f;     // (log10(5000)-2)/511

  for (int e = tid0; e < BATCH*NTOT; e += nthr){
    const int b = e / NTOT, n = e % NTOT;
    // index into MFMA-fragment-layout partials
    const int nt = n>>7, nw = (n>>6)&1, nf = (n>>4)&3, nlo = n&15;
    const int lane = (((b>>2)&3)<<4) + nlo, reg = b&3, mh = b>>4;
    const int idx = ((((nt*2+nw)*8 + mh*4+nf)*64 + lane)<<2) + reg;
    float pre = bvec[n];
    #pragma unroll
    for (int c=0;c<NCHUNK;c++) pre += partial[(size_t)c*CHUNK_F + idx];

    if (n < 512){                                    // SR dend -> SR E soma
      pre += h2f(rcur[b*KP + 512 +n])*d2s[n]
           + h2f(rcur[b*KP + 1024+n])*d2s[512+n];
    } else if (n >= 1920 && n < 2432){               // PFC dend -> PFC E soma
      const int j = n-1920;
      pre += h2f(rcur[b*KP + 2432+j])*d2s[1024+j]
           + h2f(rcur[b*KP + 2944+j])*d2s[1536+j];
    }
    if (n >= 2432 && n < 3456){                      // mGluR on PFC E dend
      const int j = n-2432;
      const float alpha = expf(-LN10*(1.0f + CEXP*(float)(j & 511)));
      const float imn = (1.f-alpha)*ime[b*1024+j] + alpha*fmaxf(pre,0.f);
      ime[b*1024+j] = imn;
      pre += imn;
    }
    const float hn = 0.8f*h[e] + 0.2f*pre + NS*noise_t[e];
    h[e] = hn;
    const float rv = is_dend(n) ? (1.f/(1.f+expf(-hn))) : fmaxf(hn,0.f);
    rnext[b*KP + n] = f2h(rv);                       // sign lives in W now
  }

  if (hasNext){
    for (int q = tid0; q < BATCH*NIN; q += nthr){
      const int b = q/NIN, j = q%NIN;
      rnext[b*KP + NTOT + j] = f2h(x_next[q]);
    }
  }

  // readout: out_t = r_t[:,SR_ES] @ w_out + b_out, one wave per (b,o)
  const int wave = tid0 >> 6;
  if (wave < BATCH*3){
    const int lane = threadIdx.x & 63;
    const int b = wave/3, o = wave%3;
    float s = 0.f;
    for (int k = lane; k < 512; k += 64) s += h2f(rcur[b*KP+k]) * w_out[k*3+o];
    #pragma unroll
    for (int off=32; off; off>>=1) s += __shfl_down(s, off);
    if (lane==0) out_t[b*3+o] = s + b_out[o];
  }
}

extern "C" void kernel_launch(void* const* d_in, const int* in_sizes, int n_in,
                              void* d_out, int out_size, void* d_ws, size_t ws_size,
                              hipStream_t stream) {
  const float* x     = (const float*)d_in[0];   // [100,32,128]
  const float* noise = (const float*)d_in[1];   // [100,32,3840]
  const float* w_rec = (const float*)d_in[2];   // [3840,3840]
  const float* w_in  = (const float*)d_in[3];   // [128,3840]
  const float* bvec  = (const float*)d_in[4];   // [3840]
  const float* d2s   = (const float*)d_in[5];   // [2048]
  const float* w_out = (const float*)d_in[6];   // [512,3]
  const float* b_out = (const float*)d_in[7];   // [3]
  const float* mask  = (const float*)d_in[8];   // [3840,3840]
  float* out = (float*)d_out;                   // [100,32,3]

  char* ws = (char*)d_ws;
  ushort* WT      = (ushort*)(ws);                      // 30,474,240 B
  float*  partial = (float*)(ws + 30474240);            // 15,237,120 B
  ushort* r0      = (ushort*)(ws + 45711360);           //    253,952 B
  ushort* r1      = (ushort*)(ws + 45965312);           //    253,952 B
  float*  h       = (float*)(ws + 46219264);            //    491,520 B
  float*  ime     = (float*)(ws + 46710784);            //    131,072 B

  k_prep_w<<<3720,256,0,stream>>>(w_rec, w_in, mask, WT);
  k_init<<<64,256,0,stream>>>(x, r0, h, ime);
  for (int t=0; t<TSTEPS; t++){
    ushort* rc = (t&1) ? r1 : r0;
    ushort* rn = (t&1) ? r0 : r1;
    k_matmul<<<992,256,0,stream>>>(WT, rc, partial);
    k_update<<<240,256,0,stream>>>(partial, bvec, d2s,
        noise + (size_t)t*BATCH*NTOT,
        x + (size_t)(t+1)*BATCH*NIN,
        rc, rn, h, ime, w_out, b_out,
        out + (size_t)t*BATCH*3,
        (t+1<TSTEPS) ? 1 : 0);
  }
}